// Round 1
// baseline (177.490 us; speedup 1.0000x reference)
//
#include <hip/hip_runtime.h>

#define T_LEN 50
#define I_IN 2
#define HID 4

__device__ __forceinline__ float EXP2(float x){
#if __has_builtin(__builtin_amdgcn_exp2f)
    return __builtin_amdgcn_exp2f(x);
#else
    return exp2f(x);
#endif
}
__device__ __forceinline__ float RCP(float x){
#if __has_builtin(__builtin_amdgcn_rcpf)
    return __builtin_amdgcn_rcpf(x);
#else
    return 1.0f/x;
#endif
}

// quad_perm DPP move: CTRL = 2-bit selector x4. Broadcast lane K: CTRL = K*0x55.
template<int CTRL>
__device__ __forceinline__ float qdpp(float v){
#if __has_builtin(__builtin_amdgcn_mov_dpp)
    return __int_as_float(__builtin_amdgcn_mov_dpp(__float_as_int(v), CTRL, 0xF, 0xF, true));
#else
    int lane = threadIdx.x & 63;
    int sel = (CTRL >> (2*(lane & 3))) & 3;
    return __shfl(v, (lane & ~3) + sel, 64);
#endif
}

// sigmoid with pre-scaled arg: gs = -log2e * pre  ->  1/(1+2^gs)
__device__ __forceinline__ float sigm_s(float gs){
    return RCP(1.0f + EXP2(gs));
}
// tanh with pre-scaled arg: gs = -2*log2e * pre  ->  2/(1+2^gs) - 1  (inf-safe)
__device__ __forceinline__ float tanh_s(float gs){
    return fmaf(2.0f, RCP(1.0f + EXP2(gs)), -1.0f);
}

__global__ __launch_bounds__(256) void lstm_fused(
    const float* __restrict__ x,
    const float* __restrict__ Wih0, const float* __restrict__ Whh0,
    const float* __restrict__ bih0, const float* __restrict__ bhh0,
    const float* __restrict__ Wih1, const float* __restrict__ Whh1,
    const float* __restrict__ bih1, const float* __restrict__ bhh1,
    const float* __restrict__ Wout, const float* __restrict__ bout,
    float* __restrict__ out, int B)
{
    __shared__ float wout_s[T_LEN*HID];
    const int tid = threadIdx.x;
    if (tid < T_LEN*HID) wout_s[tid] = Wout[tid];
    __syncthreads();

    const int gtid = blockIdx.x*256 + tid;
    const int e = gtid >> 2;      // batch element
    const int j = tid & 3;        // hidden unit owned by this lane
    if (e >= B) return;

    const float S1 = -1.4426950408889634f;   // -log2(e)
    const float S2 = -2.8853900817779268f;   // -2*log2(e)

    // Per-lane weights for unit j. PyTorch gate rows: i:0-3 f:4-7 g:8-11 o:12-15.
    float wx0[4][2], wh0[4][4], b0[4];
    float wx1[4][4], wh1[4][4], b1[4];
#pragma unroll
    for (int G = 0; G < 4; ++G){
        const float s = (G == 2) ? S2 : S1;
        const int r = G*4 + j;
        wx0[G][0] = Wih0[r*2+0]*s;
        wx0[G][1] = Wih0[r*2+1]*s;
#pragma unroll
        for (int k = 0; k < 4; ++k){
            wh0[G][k] = Whh0[r*4+k]*s;
            wx1[G][k] = Wih1[r*4+k]*s;
            wh1[G][k] = Whh1[r*4+k]*s;
        }
        b0[G] = (bih0[r] + bhh0[r])*s;
        b1[G] = (bih1[r] + bhh1[r])*s;
    }

    float h0 = 0.f, c0 = 0.f, h1 = 0.f, c1 = 0.f, acc = 0.f;
    const float* xp = x + (size_t)e * (T_LEN*I_IN);

#pragma unroll 2
    for (int t = 0; t < T_LEN; ++t){
        const float2 xv = *reinterpret_cast<const float2*>(xp + t*2);

        // ---- layer 0 ----
        const float h00 = qdpp<0x00>(h0), h01 = qdpp<0x55>(h0),
                    h02 = qdpp<0xAA>(h0), h03 = qdpp<0xFF>(h0);
        float g[4];
#pragma unroll
        for (int G = 0; G < 4; ++G){
            float a = fmaf(wx0[G][0], xv.x, b0[G]);
            a = fmaf(wx0[G][1], xv.y, a);
            a = fmaf(wh0[G][0], h00, a);
            a = fmaf(wh0[G][1], h01, a);
            a = fmaf(wh0[G][2], h02, a);
            a = fmaf(wh0[G][3], h03, a);
            g[G] = a;
        }
        {
            const float si = sigm_s(g[0]);
            const float sf = sigm_s(g[1]);
            const float tg = tanh_s(g[2]);
            const float so = sigm_s(g[3]);
            c0 = fmaf(sf, c0, si*tg);
            h0 = so * tanh_s(c0 * S2);
        }

        // ---- layer 1 ----
        const float a0 = qdpp<0x00>(h0), a1 = qdpp<0x55>(h0),
                    a2 = qdpp<0xAA>(h0), a3 = qdpp<0xFF>(h0);
        const float p0 = qdpp<0x00>(h1), p1 = qdpp<0x55>(h1),
                    p2 = qdpp<0xAA>(h1), p3 = qdpp<0xFF>(h1);
#pragma unroll
        for (int G = 0; G < 4; ++G){
            float a = fmaf(wx1[G][0], a0, b1[G]);
            a = fmaf(wx1[G][1], a1, a);
            a = fmaf(wx1[G][2], a2, a);
            a = fmaf(wx1[G][3], a3, a);
            a = fmaf(wh1[G][0], p0, a);
            a = fmaf(wh1[G][1], p1, a);
            a = fmaf(wh1[G][2], p2, a);
            a = fmaf(wh1[G][3], p3, a);
            g[G] = a;
        }
        {
            const float si = sigm_s(g[0]);
            const float sf = sigm_s(g[1]);
            const float tg = tanh_s(g[2]);
            const float so = sigm_s(g[3]);
            c1 = fmaf(sf, c1, si*tg);
            h1 = so * tanh_s(c1 * S2);
        }

        acc = fmaf(h1, wout_s[t*4 + j], acc);
    }

    // quad reduction of acc: xor1 = quad_perm[1,0,3,2]=0xB1, xor2 = [2,3,0,1]=0x4E
    acc += qdpp<0xB1>(acc);
    acc += qdpp<0x4E>(acc);

    if (j == 0){
        const float z = acc + bout[0];
        out[e] = RCP(1.0f + EXP2(z * S1));   // sigmoid(z)
    }
}

extern "C" void kernel_launch(void* const* d_in, const int* in_sizes, int n_in,
                              void* d_out, int out_size, void* d_ws, size_t ws_size,
                              hipStream_t stream)
{
    const float* x    = (const float*)d_in[0];
    const float* Wih0 = (const float*)d_in[1];
    const float* Whh0 = (const float*)d_in[2];
    const float* bih0 = (const float*)d_in[3];
    const float* bhh0 = (const float*)d_in[4];
    const float* Wih1 = (const float*)d_in[5];
    const float* Whh1 = (const float*)d_in[6];
    const float* bih1 = (const float*)d_in[7];
    const float* bhh1 = (const float*)d_in[8];
    const float* Wout = (const float*)d_in[9];
    const float* bout = (const float*)d_in[10];
    float* out = (float*)d_out;

    const int B = in_sizes[0] / (T_LEN*I_IN);
    const int total = B * 4;
    const int threads = 256;
    const int blocks = (total + threads - 1) / threads;
    lstm_fused<<<blocks, threads, 0, stream>>>(x, Wih0, Whh0, bih0, bhh0,
                                               Wih1, Whh1, bih1, bhh1,
                                               Wout, bout, out, B);
}

// Round 3
// 152.901 us; speedup vs baseline: 1.1608x; 1.1608x over previous
//
#include <hip/hip_runtime.h>

#define T_LEN 50
#define I_IN 2
#define HID 4

typedef _Float16 hf2 __attribute__((ext_vector_type(2)));
typedef __fp16   fp2 __attribute__((ext_vector_type(2)));

__device__ __forceinline__ float EXP2(float x){
#if __has_builtin(__builtin_amdgcn_exp2f)
    return __builtin_amdgcn_exp2f(x);
#else
    return exp2f(x);
#endif
}
__device__ __forceinline__ float RCP(float x){
#if __has_builtin(__builtin_amdgcn_rcpf)
    return __builtin_amdgcn_rcpf(x);
#else
    return 1.0f/x;
#endif
}
__device__ __forceinline__ hf2 PK(float a, float b){
#if __has_builtin(__builtin_amdgcn_cvt_pkrtz)
    return __builtin_bit_cast(hf2, __builtin_amdgcn_cvt_pkrtz(a, b));
#else
    hf2 r; r.x = (_Float16)a; r.y = (_Float16)b; return r;
#endif
}
__device__ __forceinline__ float DOT2(hf2 a, hf2 b, float c){
#if __has_builtin(__builtin_amdgcn_fdot2)
    return __builtin_amdgcn_fdot2(a, b, c, false);
#else
    return c + (float)a.x*(float)b.x + (float)a.y*(float)b.y;
#endif
}

// quad_perm DPP move: CTRL = 2-bit selector x4. Broadcast lane K: CTRL = K*0x55.
template<int CTRL>
__device__ __forceinline__ float qdpp(float v){
#if __has_builtin(__builtin_amdgcn_mov_dpp)
    return __int_as_float(__builtin_amdgcn_mov_dpp(__float_as_int(v), CTRL, 0xF, 0xF, true));
#else
    int lane = threadIdx.x & 63;
    int sel = (CTRL >> (2*(lane & 3))) & 3;
    return __shfl(v, (lane & ~3) + sel, 64);
#endif
}

// Fused LSTM pointwise stage, one hidden unit per lane.
// Inputs pre-scaled: gi,gf,go by S1=-log2e; gg by S2=-2log2e.
// sigma(f)=1/A (A=1+r), sigma(i)=1/B (B=1+p), tanh(g)=(1-q)/C (C=1+q)
// c' = c/A + (1-q)/(B*C) = [c*B*C + (1-q)*A] * rcp(A*B*C)
// h  = sigma(o)*tanh(c') = (1-u)*rcp((1+s)(1+u)),  s=2^{S1*o}, u=2^{S2*c'}
__device__ __forceinline__ void lstm_act(const float g[4], float& c, float& h){
    const float S2 = -2.8853900817779268f;
    const float p = EXP2(g[0]);
    const float r = EXP2(g[1]);
    const float q = EXP2(g[2]);
    const float A = 1.0f + r;
    const float Bv = 1.0f + p;
    const float Cv = 1.0f + q;
    const float BC = Bv * Cv;
    const float num = fmaf(c, BC, (1.0f - q) * A);
    c = num * RCP(A * BC);
    const float s = EXP2(g[3]);
    const float u = EXP2(fminf(c * S2, 126.0f));   // clamp: avoid inf -> NaN
    h = (1.0f - u) * RCP((1.0f + s) * (1.0f + u));
}

__global__ __launch_bounds__(256) void lstm_fused(
    const float* __restrict__ x,
    const float* __restrict__ Wih0, const float* __restrict__ Whh0,
    const float* __restrict__ bih0, const float* __restrict__ bhh0,
    const float* __restrict__ Wih1, const float* __restrict__ Whh1,
    const float* __restrict__ bih1, const float* __restrict__ bhh1,
    const float* __restrict__ Wout, const float* __restrict__ bout,
    float* __restrict__ out, int B)
{
    __shared__ float wout_s[T_LEN*HID];
    const int tid = threadIdx.x;
    if (tid < T_LEN*HID) wout_s[tid] = Wout[tid];
    __syncthreads();

    const int gtid = blockIdx.x*256 + tid;
    const int e = gtid >> 2;      // batch element
    const int j = tid & 3;        // hidden unit owned by this lane
    if (e >= B) return;

    const float S1 = -1.4426950408889634f;   // -log2(e)
    const float S2 = -2.8853900817779268f;   // -2*log2(e)

    // Per-lane weights for unit j. PyTorch gate rows: i:0-3 f:4-7 g:8-11 o:12-15.
    float wx0[4][2], b0[4], b1[4];
    hf2 wh0p[4][2], wx1p[4][2], wh1p[4][2];
#pragma unroll
    for (int G = 0; G < 4; ++G){
        const float s = (G == 2) ? S2 : S1;
        const int r = G*4 + j;
        wx0[G][0] = Wih0[r*2+0]*s;
        wx0[G][1] = Wih0[r*2+1]*s;
        wh0p[G][0] = PK(Whh0[r*4+0]*s, Whh0[r*4+1]*s);
        wh0p[G][1] = PK(Whh0[r*4+2]*s, Whh0[r*4+3]*s);
        wx1p[G][0] = PK(Wih1[r*4+0]*s, Wih1[r*4+1]*s);
        wx1p[G][1] = PK(Wih1[r*4+2]*s, Wih1[r*4+3]*s);
        wh1p[G][0] = PK(Whh1[r*4+0]*s, Whh1[r*4+1]*s);
        wh1p[G][1] = PK(Whh1[r*4+2]*s, Whh1[r*4+3]*s);
        b0[G] = (bih0[r] + bhh0[r])*s;
        b1[G] = (bih1[r] + bhh1[r])*s;
    }

    float h0 = 0.f, c0 = 0.f, h1 = 0.f, c1 = 0.f, acc = 0.f;
    hf2 h0p[2] = { hf2{0,0}, hf2{0,0} };
    hf2 h1p[2] = { hf2{0,0}, hf2{0,0} };
    const float* xp = x + (size_t)e * (T_LEN*I_IN);

#pragma unroll 2
    for (int t = 0; t < T_LEN; ++t){
        const float2 xv = *reinterpret_cast<const float2*>(xp + t*2);

        // ---- layer 0 gates (x in f32 fma, h in f16 dot2) ----
        float g[4];
#pragma unroll
        for (int G = 0; G < 4; ++G){
            float a = fmaf(wx0[G][0], xv.x, b0[G]);
            a = fmaf(wx0[G][1], xv.y, a);
            a = DOT2(wh0p[G][0], h0p[0], a);
            a = DOT2(wh0p[G][1], h0p[1], a);
            g[G] = a;
        }
        lstm_act(g, c0, h0);

        // broadcast + pack new h0 (used by layer1 now AND layer0 next step)
        {
            const float f0 = qdpp<0x00>(h0), f1 = qdpp<0x55>(h0),
                        f2 = qdpp<0xAA>(h0), f3 = qdpp<0xFF>(h0);
            h0p[0] = PK(f0, f1);
            h0p[1] = PK(f2, f3);
        }

        // ---- layer 1 gates (all f16 dot2) ----
#pragma unroll
        for (int G = 0; G < 4; ++G){
            float a = DOT2(wx1p[G][0], h0p[0], b1[G]);
            a = DOT2(wx1p[G][1], h0p[1], a);
            a = DOT2(wh1p[G][0], h1p[0], a);
            a = DOT2(wh1p[G][1], h1p[1], a);
            g[G] = a;
        }
        lstm_act(g, c1, h1);

        // broadcast + pack new h1 (used by layer1 next step)
        {
            const float f0 = qdpp<0x00>(h1), f1 = qdpp<0x55>(h1),
                        f2 = qdpp<0xAA>(h1), f3 = qdpp<0xFF>(h1);
            h1p[0] = PK(f0, f1);
            h1p[1] = PK(f2, f3);
        }

        acc = fmaf(h1, wout_s[t*4 + j], acc);
    }

    // quad reduction of acc: xor1 = quad_perm[1,0,3,2]=0xB1, xor2 = [2,3,0,1]=0x4E
    acc += qdpp<0xB1>(acc);
    acc += qdpp<0x4E>(acc);

    if (j == 0){
        const float z = acc + bout[0];
        out[e] = RCP(1.0f + EXP2(z * S1));   // sigmoid(z)
    }
}

extern "C" void kernel_launch(void* const* d_in, const int* in_sizes, int n_in,
                              void* d_out, int out_size, void* d_ws, size_t ws_size,
                              hipStream_t stream)
{
    const float* x    = (const float*)d_in[0];
    const float* Wih0 = (const float*)d_in[1];
    const float* Whh0 = (const float*)d_in[2];
    const float* bih0 = (const float*)d_in[3];
    const float* bhh0 = (const float*)d_in[4];
    const float* Wih1 = (const float*)d_in[5];
    const float* Whh1 = (const float*)d_in[6];
    const float* bih1 = (const float*)d_in[7];
    const float* bhh1 = (const float*)d_in[8];
    const float* Wout = (const float*)d_in[9];
    const float* bout = (const float*)d_in[10];
    float* out = (float*)d_out;

    const int B = in_sizes[0] / (T_LEN*I_IN);
    const int total = B * 4;
    const int threads = 256;
    const int blocks = (total + threads - 1) / threads;
    lstm_fused<<<blocks, threads, 0, stream>>>(x, Wih0, Whh0, bih0, bhh0,
                                               Wih1, Whh1, bih1, bhh1,
                                               Wout, bout, out, B);
}

// Round 4
// 149.356 us; speedup vs baseline: 1.1884x; 1.0237x over previous
//
#include <hip/hip_runtime.h>

#define T_LEN 50
#define I_IN 2
#define HID 4

typedef _Float16 hf2 __attribute__((ext_vector_type(2)));

__device__ __forceinline__ float EXP2(float x){
#if __has_builtin(__builtin_amdgcn_exp2f)
    return __builtin_amdgcn_exp2f(x);
#else
    return exp2f(x);
#endif
}
__device__ __forceinline__ float RCP(float x){
#if __has_builtin(__builtin_amdgcn_rcpf)
    return __builtin_amdgcn_rcpf(x);
#else
    return 1.0f/x;
#endif
}
__device__ __forceinline__ hf2 PK(float a, float b){
#if __has_builtin(__builtin_amdgcn_cvt_pkrtz)
    return __builtin_bit_cast(hf2, __builtin_amdgcn_cvt_pkrtz(a, b));
#else
    hf2 r; r.x = (_Float16)a; r.y = (_Float16)b; return r;
#endif
}
__device__ __forceinline__ float DOT2(hf2 a, hf2 b, float c){
#if __has_builtin(__builtin_amdgcn_fdot2)
    return __builtin_amdgcn_fdot2(a, b, c, false);
#else
    return c + (float)a.x*(float)b.x + (float)a.y*(float)b.y;
#endif
}

// quad_perm DPP move on raw bits. Broadcast lane K of quad: CTRL=K*0x55.
// Swap pairs [1,0,3,2]: 0xB1.
template<int CTRL>
__device__ __forceinline__ int qdpp_i(int v){
#if __has_builtin(__builtin_amdgcn_mov_dpp)
    return __builtin_amdgcn_mov_dpp(v, CTRL, 0xF, 0xF, true);
#else
    int lane = threadIdx.x & 63;
    int sel = (CTRL >> (2*(lane & 3))) & 3;
    return __shfl(v, (lane & ~3) + sel, 64);
#endif
}
template<int CTRL>
__device__ __forceinline__ float qdpp(float v){
    return __int_as_float(qdpp_i<CTRL>(__float_as_int(v)));
}
template<int CTRL>
__device__ __forceinline__ hf2 qdpp_h(hf2 v){
    return __builtin_bit_cast(hf2, qdpp_i<CTRL>(__builtin_bit_cast(int, v)));
}

// Fused LSTM pointwise stage, one hidden unit per lane.
// Gate pre-activations pre-scaled: i,f,o by S1=-log2e; g by S2=-2log2e.
// c' = [c*B*C + (1-q)*A] * rcp(A*B*C)  with p,r,q = 2^{scaled gates}
// h  = (1-u)*rcp((1+s)(1+u)),  s=2^{S1*o}, u=2^{S2*c'}  (clamped, inf-safe)
__device__ __forceinline__ void lstm_act(const float g[4], float& c, float& h){
    const float S2 = -2.8853900817779268f;
    const float p = EXP2(g[0]);
    const float r = EXP2(g[1]);
    const float q = EXP2(g[2]);
    const float A = 1.0f + r;
    const float Bv = 1.0f + p;
    const float Cv = 1.0f + q;
    const float BC = Bv * Cv;
    const float num = fmaf(c, BC, (1.0f - q) * A);
    c = num * RCP(A * BC);
    const float s = EXP2(g[3]);
    const float u = EXP2(fminf(c * S2, 126.0f));
    h = (1.0f - u) * RCP((1.0f + s) * (1.0f + u));
}

// broadcast+pack: from per-lane h (unit j in lane j of quad) build (h0,h1),(h2,h3)
__device__ __forceinline__ void bpack(float h, hf2& lo, hf2& hi){
    const float hs = qdpp<0xB1>(h);       // neighbor's h
    const hf2 hh = PK(h, hs);             // lane0:(h0,h1) lane2:(h2,h3)
    lo = qdpp_h<0x00>(hh);
    hi = qdpp_h<0xAA>(hh);
}

__global__ __launch_bounds__(256) void lstm_fused(
    const float* __restrict__ x,
    const float* __restrict__ Wih0, const float* __restrict__ Whh0,
    const float* __restrict__ bih0, const float* __restrict__ bhh0,
    const float* __restrict__ Wih1, const float* __restrict__ Whh1,
    const float* __restrict__ bih1, const float* __restrict__ bhh1,
    const float* __restrict__ Wout, const float* __restrict__ bout,
    float* __restrict__ out, int B)
{
    __shared__ float wout_s[T_LEN*HID];
    const int tid = threadIdx.x;
    if (tid < T_LEN*HID) wout_s[tid] = Wout[tid];
    __syncthreads();

    const int gtid = blockIdx.x*256 + tid;
    const int e = gtid >> 2;      // batch element
    const int j = tid & 3;        // hidden unit owned by this lane
    if (e >= B) return;

    const float S1 = -1.4426950408889634f;   // -log2(e)
    const float S2 = -2.8853900817779268f;   // -2*log2(e)

    // Per-lane weights for unit j. PyTorch gate rows: i:0-3 f:4-7 g:8-11 o:12-15.
    float b0[4], b1[4];
    hf2 wx0p[4], wh0p[4][2], wx1p[4][2], wh1p[4][2];
#pragma unroll
    for (int G = 0; G < 4; ++G){
        const float s = (G == 2) ? S2 : S1;
        const int r = G*4 + j;
        wx0p[G]    = PK(Wih0[r*2+0]*s, Wih0[r*2+1]*s);
        wh0p[G][0] = PK(Whh0[r*4+0]*s, Whh0[r*4+1]*s);
        wh0p[G][1] = PK(Whh0[r*4+2]*s, Whh0[r*4+3]*s);
        wx1p[G][0] = PK(Wih1[r*4+0]*s, Wih1[r*4+1]*s);
        wx1p[G][1] = PK(Wih1[r*4+2]*s, Wih1[r*4+3]*s);
        wh1p[G][0] = PK(Whh1[r*4+0]*s, Whh1[r*4+1]*s);
        wh1p[G][1] = PK(Whh1[r*4+2]*s, Whh1[r*4+3]*s);
        b0[G] = (bih0[r] + bhh0[r])*s;
        b1[G] = (bih1[r] + bhh1[r])*s;
    }

    float h0 = 0.f, c0 = 0.f, h1 = 0.f, c1 = 0.f, acc = 0.f;
    hf2 h0p[2] = { hf2{0,0}, hf2{0,0} };
    hf2 h1p[2] = { hf2{0,0}, hf2{0,0} };
    const float* xp = x + (size_t)e * (T_LEN*I_IN);

    auto step = [&](hf2 xpk, int t){
        // ---- layer 0 gates (x packed f16 dot2, h f16 dot2) ----
        float g[4];
#pragma unroll
        for (int G = 0; G < 4; ++G){
            float a = DOT2(wx0p[G], xpk, b0[G]);
            a = DOT2(wh0p[G][0], h0p[0], a);
            a = DOT2(wh0p[G][1], h0p[1], a);
            g[G] = a;
        }
        lstm_act(g, c0, h0);
        bpack(h0, h0p[0], h0p[1]);

        // ---- layer 1 gates ----
#pragma unroll
        for (int G = 0; G < 4; ++G){
            float a = DOT2(wx1p[G][0], h0p[0], b1[G]);
            a = DOT2(wx1p[G][1], h0p[1], a);
            a = DOT2(wh1p[G][0], h1p[0], a);
            a = DOT2(wh1p[G][1], h1p[1], a);
            g[G] = a;
        }
        lstm_act(g, c1, h1);
        bpack(h1, h1p[0], h1p[1]);

        acc = fmaf(h1, wout_s[t*4 + j], acc);
    };

#pragma unroll 5
    for (int tt = 0; tt < T_LEN/2; ++tt){
        const float4 xv = *reinterpret_cast<const float4*>(xp + tt*4);
        step(PK(xv.x, xv.y), 2*tt);
        step(PK(xv.z, xv.w), 2*tt + 1);
    }

    // quad reduction of acc: xor1 = quad_perm[1,0,3,2]=0xB1, xor2 = [2,3,0,1]=0x4E
    acc += qdpp<0xB1>(acc);
    acc += qdpp<0x4E>(acc);

    if (j == 0){
        const float z = acc + bout[0];
        out[e] = RCP(1.0f + EXP2(z * S1));   // sigmoid(z)
    }
}

extern "C" void kernel_launch(void* const* d_in, const int* in_sizes, int n_in,
                              void* d_out, int out_size, void* d_ws, size_t ws_size,
                              hipStream_t stream)
{
    const float* x    = (const float*)d_in[0];
    const float* Wih0 = (const float*)d_in[1];
    const float* Whh0 = (const float*)d_in[2];
    const float* bih0 = (const float*)d_in[3];
    const float* bhh0 = (const float*)d_in[4];
    const float* Wih1 = (const float*)d_in[5];
    const float* Whh1 = (const float*)d_in[6];
    const float* bih1 = (const float*)d_in[7];
    const float* bhh1 = (const float*)d_in[8];
    const float* Wout = (const float*)d_in[9];
    const float* bout = (const float*)d_in[10];
    float* out = (float*)d_out;

    const int B = in_sizes[0] / (T_LEN*I_IN);
    const int total = B * 4;
    const int threads = 256;
    const int blocks = (total + threads - 1) / threads;
    lstm_fused<<<blocks, threads, 0, stream>>>(x, Wih0, Whh0, bih0, bhh0,
                                               Wih1, Whh1, bih1, bhh1,
                                               Wout, bout, out, B);
}